// Round 3
// baseline (419.387 us; speedup 1.0000x reference)
//
#include <hip/hip_runtime.h>
#include <hip/hip_bf16.h>

#define B  32
#define T  8192
#define H  256
#define NC 32      // T-chunks per batch
#define CT 256     // rows per chunk (NC*CT == T)

// ---------------------------------------------------------------------------
// Kernel 1: v[b,h] = sum_o W1[o,h] * h_t[b,o],   h_t[b] = hs[b, T-1, :]
// score[b,t] = hs[b,t,:] . v[b]  algebraically replaces the (B,T,H) einsum.
// ---------------------------------------------------------------------------
__global__ void k_v(const float* __restrict__ hs,
                    const float* __restrict__ W1,
                    float* __restrict__ v) {
    int b = blockIdx.x, tid = threadIdx.x;  // 256 threads
    __shared__ float ht[H];
    ht[tid] = hs[((size_t)(b * T + (T - 1))) * H + tid];
    __syncthreads();
    float acc = 0.f;
    #pragma unroll 8
    for (int o = 0; o < H; ++o)
        acc += W1[o * H + tid] * ht[o];     // coalesced over tid
    v[b * H + tid] = acc;
}

// ---------------------------------------------------------------------------
// Kernel 2 (fused, single pass over hs): per (b, chunk) block of 256 rows:
//   raw score[b,t] (to ws) + online-softmax partials (m,l) + partial context.
// 4 waves/block; wave handles 64 rows in 16 steps of 4 rows.
// Lane layout: r = lane>>4 (row within step), c = lane&15 (16-col slice).
// Shuffle-reduce over 16 lanes (xor 1,2,4,8) — 4 DS ops per 4 rows.
// ---------------------------------------------------------------------------
__global__ void __launch_bounds__(256, 4)
k_fused(const float* __restrict__ hs,
        const float* __restrict__ v,
        float* __restrict__ score,
        float* __restrict__ mpart,
        float* __restrict__ lpart,
        float* __restrict__ ctxp) {
    int b = blockIdx.x, tc = blockIdx.y;
    int tid = threadIdx.x, wave = tid >> 6, lane = tid & 63;
    int r = lane >> 4, c = lane & 15;

    __shared__ float vs[H];
    __shared__ float wm[16], wl[16];
    __shared__ float wctx[16][H];           // 16 KB
    vs[tid] = v[b * H + tid];
    __syncthreads();

    float4 vv0 = *(const float4*)(vs + c * 16 + 0);
    float4 vv1 = *(const float4*)(vs + c * 16 + 4);
    float4 vv2 = *(const float4*)(vs + c * 16 + 8);
    float4 vv3 = *(const float4*)(vs + c * 16 + 12);

    const float* base = hs + ((size_t)(b * T + tc * CT)) * H;
    float m = -1e30f, l = 0.f;
    float4 c0 = {0,0,0,0}, c1 = {0,0,0,0}, c2 = {0,0,0,0}, c3 = {0,0,0,0};

    for (int g = 0; g < 16; ++g) {
        int row = wave * 64 + g * 4 + r;
        const float* rp = base + (size_t)row * H + c * 16;
        float4 u0 = *(const float4*)(rp + 0);
        float4 u1 = *(const float4*)(rp + 4);
        float4 u2 = *(const float4*)(rp + 8);
        float4 u3 = *(const float4*)(rp + 12);
        float s = u0.x*vv0.x + u0.y*vv0.y + u0.z*vv0.z + u0.w*vv0.w
                + u1.x*vv1.x + u1.y*vv1.y + u1.z*vv1.z + u1.w*vv1.w
                + u2.x*vv2.x + u2.y*vv2.y + u2.z*vv2.z + u2.w*vv2.w
                + u3.x*vv3.x + u3.y*vv3.y + u3.z*vv3.z + u3.w*vv3.w;
        s += __shfl_xor(s, 1, 64);
        s += __shfl_xor(s, 2, 64);
        s += __shfl_xor(s, 4, 64);
        s += __shfl_xor(s, 8, 64);          // all 16 lanes of group have dot
        if (c == 0)
            score[b * T + tc * CT + row] = s;
        float mn = fmaxf(m, s);
        float al = __expf(m - mn);          // first step: __expf(-inf) = 0
        float p  = __expf(s - mn);
        l = l * al + p;
        c0.x = c0.x*al + p*u0.x; c0.y = c0.y*al + p*u0.y;
        c0.z = c0.z*al + p*u0.z; c0.w = c0.w*al + p*u0.w;
        c1.x = c1.x*al + p*u1.x; c1.y = c1.y*al + p*u1.y;
        c1.z = c1.z*al + p*u1.z; c1.w = c1.w*al + p*u1.w;
        c2.x = c2.x*al + p*u2.x; c2.y = c2.y*al + p*u2.y;
        c2.z = c2.z*al + p*u2.z; c2.w = c2.w*al + p*u2.w;
        c3.x = c3.x*al + p*u3.x; c3.y = c3.y*al + p*u3.y;
        c3.z = c3.z*al + p*u3.z; c3.w = c3.w*al + p*u3.w;
        m = mn;
    }

    // 16 partials per block: (wave, r) each with (m, l, c[256-col slice set])
    int part = wave * 4 + r;
    *(float4*)(&wctx[part][c * 16 + 0])  = c0;
    *(float4*)(&wctx[part][c * 16 + 4])  = c1;
    *(float4*)(&wctx[part][c * 16 + 8])  = c2;
    *(float4*)(&wctx[part][c * 16 + 12]) = c3;
    if (c == 0) { wm[part] = m; wl[part] = l; }
    __syncthreads();

    float bm = -1e30f;
    #pragma unroll
    for (int k = 0; k < 16; ++k) bm = fmaxf(bm, wm[k]);
    float cc = 0.f, L = 0.f;
    #pragma unroll
    for (int k = 0; k < 16; ++k) {
        float e = __expf(wm[k] - bm);
        cc += wctx[k][tid] * e;
        L  += wl[k] * e;
    }
    ctxp[((size_t)(b * NC + tc)) * H + tid] = cc;
    if (tid == 0) {
        mpart[b * NC + tc] = bm;
        lpart[b * NC + tc] = L;     // L identical across tid; write once
    }
}

// ---------------------------------------------------------------------------
// Kernel 3: combine chunk partials -> ctx[b,:]; pre = [ctx, h_t];
//           out_av[b,o] = tanh( pre . W2[o,:] ).  Also writes (M,L) stats.
// ---------------------------------------------------------------------------
__global__ void k_final(const float* __restrict__ hs,
                        const float* __restrict__ W2,
                        const float* __restrict__ ctxp,
                        const float* __restrict__ mpart,
                        const float* __restrict__ lpart,
                        float* __restrict__ stats,
                        float* __restrict__ out_av) {
    int b = blockIdx.x, tid = threadIdx.x;  // 256 threads
    __shared__ float pre[2 * H];
    float M = -1e30f;
    for (int c = 0; c < NC; ++c) M = fmaxf(M, mpart[b * NC + c]);
    float L = 0.f, cc = 0.f;
    for (int c = 0; c < NC; ++c) {
        float e = __expf(mpart[b * NC + c] - M);
        L  += lpart[b * NC + c] * e;
        cc += ctxp[((size_t)(b * NC + c)) * H + tid] * e;
    }
    pre[tid]     = cc / L;
    pre[H + tid] = hs[((size_t)(b * T + (T - 1))) * H + tid];
    if (tid == 0) { stats[b * 2] = M; stats[b * 2 + 1] = L; }
    __syncthreads();
    const float4* w2r = (const float4*)(W2 + (size_t)tid * (2 * H));
    float acc = 0.f;
    #pragma unroll 4
    for (int j = 0; j < (2 * H) / 4; ++j) {
        float4 u = w2r[j];
        acc += pre[4 * j + 0] * u.x + pre[4 * j + 1] * u.y
             + pre[4 * j + 2] * u.z + pre[4 * j + 3] * u.w;
    }
    out_av[b * H + tid] = tanhf(acc);
}

// ---------------------------------------------------------------------------
// Kernel 4: attention_weights[b,t] = exp(score[b,t] - M[b]) / L[b]
// ---------------------------------------------------------------------------
__global__ void k_weights(const float* __restrict__ score,
                          const float* __restrict__ stats,
                          float* __restrict__ out_aw) {
    int b = blockIdx.x;
    int t = blockIdx.y * 1024 + threadIdx.x;
    float M = stats[b * 2];
    float invL = 1.0f / stats[b * 2 + 1];
    out_aw[b * T + t] = __expf(score[b * T + t] - M) * invL;
}

extern "C" void kernel_launch(void* const* d_in, const int* in_sizes, int n_in,
                              void* d_out, int out_size, void* d_ws, size_t ws_size,
                              hipStream_t stream) {
    const float* hs = (const float*)d_in[0];
    const float* W1 = (const float*)d_in[1];
    const float* W2 = (const float*)d_in[2];
    float* out    = (float*)d_out;
    float* out_av = out;              // attention_vector  [B*H  = 8192]
    float* out_aw = out + B * H;      // attention_weights [B*T  = 262144]

    float* ws    = (float*)d_ws;
    float* v     = ws;                              // 8192
    float* score = v + B * H;                       // 262144
    float* mpart = score + B * T;                   // 1024
    float* lpart = mpart + B * NC;                  // 1024
    float* ctxp  = lpart + B * NC;                  // 262144
    float* stats = ctxp + (size_t)B * NC * H;       // 64
    // total ws: ~2.1 MB

    k_v      <<<dim3(B),       256,  0, stream>>>(hs, W1, v);
    k_fused  <<<dim3(B, NC),   256,  0, stream>>>(hs, v, score, mpart, lpart, ctxp);
    k_final  <<<dim3(B),       256,  0, stream>>>(hs, W2, ctxp, mpart, lpart, stats, out_av);
    k_weights<<<dim3(B, 8),    1024, 0, stream>>>(score, stats, out_aw);
}

// Round 4
// 388.152 us; speedup vs baseline: 1.0805x; 1.0805x over previous
//
#include <hip/hip_runtime.h>
#include <hip/hip_bf16.h>

#define B  32
#define T  8192
#define H  256
#define NC 32      // T-chunks per batch
#define CT 256     // rows per chunk (NC*CT == T)
#define VQ 8       // o-slices for k_v partials

// ---------------------------------------------------------------------------
// Kernel 1: vpart[q][b][h] = sum_{o in slice q} W1[o,h] * h_t[b,o]
// (v[b] = W1^T h_t[b]; score[b,t] = hs[b,t,:].v[b] replaces the big einsum)
// grid (B, VQ) so 256 blocks -> all CUs busy, short 32-deep chains.
// ---------------------------------------------------------------------------
__global__ void k_v(const float* __restrict__ hs,
                    const float* __restrict__ W1,
                    float* __restrict__ vpart) {
    int b = blockIdx.x, q = blockIdx.y, tid = threadIdx.x;  // 256 threads
    __shared__ float ht[32];
    if (tid < 32) ht[tid] = hs[((size_t)(b * T + (T - 1))) * H + q * 32 + tid];
    __syncthreads();
    float acc = 0.f;
    #pragma unroll
    for (int o = 0; o < 32; ++o)
        acc += W1[(q * 32 + o) * H + tid] * ht[o];   // coalesced over tid
    vpart[((size_t)(q * B + b)) * H + tid] = acc;
}

// ---------------------------------------------------------------------------
// Kernel 2 (fused, single pass over hs): per (b, chunk) block of 256 rows:
//   raw score[b,t] (to ws) + online-softmax partials (m,l) + partial context.
// R2-proven core: wave owns 64 rows, lane owns 4 cols (float4, perfectly
// coalesced 1 KB/load); 6-step xor-shuffle gives every lane the row dot.
// ---------------------------------------------------------------------------
__global__ void __launch_bounds__(256, 4)
k_fused(const float* __restrict__ hs,
        const float* __restrict__ vpart,
        float* __restrict__ score,
        float* __restrict__ mpart,
        float* __restrict__ lpart,
        float* __restrict__ ctxp) {
    int b = blockIdx.x, tc = blockIdx.y;
    int tid = threadIdx.x, wave = tid >> 6, lane = tid & 63;
    __shared__ float vs[H];
    __shared__ float wm[4], wl[4];
    __shared__ float wctx[4][H];

    float vv = 0.f;
    #pragma unroll
    for (int q = 0; q < VQ; ++q)
        vv += vpart[((size_t)(q * B + b)) * H + tid];
    vs[tid] = vv;
    __syncthreads();
    float v0 = vs[lane * 4 + 0], v1 = vs[lane * 4 + 1];
    float v2 = vs[lane * 4 + 2], v3 = vs[lane * 4 + 3];

    const float* base = hs + ((size_t)(b * T + tc * CT)) * H;
    float m = -1e30f, l = 0.f;
    float c0 = 0.f, c1 = 0.f, c2 = 0.f, c3 = 0.f;

    for (int i = 0; i < 64; ++i) {
        int row = wave * 64 + i;
        float4 u = *(const float4*)(base + (size_t)row * H + lane * 4);
        float s = u.x * v0 + u.y * v1 + u.z * v2 + u.w * v3;
        #pragma unroll
        for (int mk = 1; mk < 64; mk <<= 1)
            s += __shfl_xor(s, mk, 64);      // all lanes end with full dot
        if (lane == 0)
            score[b * T + tc * CT + row] = s;
        float mn = fmaxf(m, s);
        float al = __expf(m - mn);           // first iter: __expf(-huge) = 0
        float p  = __expf(s - mn);
        l  = l  * al + p;
        c0 = c0 * al + p * u.x;
        c1 = c1 * al + p * u.y;
        c2 = c2 * al + p * u.z;
        c3 = c3 * al + p * u.w;
        m  = mn;
    }

    if (lane == 0) { wm[wave] = m; wl[wave] = l; }
    wctx[wave][lane * 4 + 0] = c0;
    wctx[wave][lane * 4 + 1] = c1;
    wctx[wave][lane * 4 + 2] = c2;
    wctx[wave][lane * 4 + 3] = c3;
    __syncthreads();

    float bm = fmaxf(fmaxf(wm[0], wm[1]), fmaxf(wm[2], wm[3]));
    float e0 = __expf(wm[0] - bm), e1 = __expf(wm[1] - bm);
    float e2 = __expf(wm[2] - bm), e3 = __expf(wm[3] - bm);
    float cc = wctx[0][tid] * e0 + wctx[1][tid] * e1
             + wctx[2][tid] * e2 + wctx[3][tid] * e3;
    ctxp[((size_t)(b * NC + tc)) * H + tid] = cc;
    if (tid == 0) {
        mpart[b * NC + tc] = bm;
        lpart[b * NC + tc] = wl[0] * e0 + wl[1] * e1 + wl[2] * e2 + wl[3] * e3;
    }
}

// ---------------------------------------------------------------------------
// Kernel 3 (epilogue, one launch): grid (B, NC+1).
// Every block recomputes M,L from the tiny mpart/lpart (128 B each, L2) —
// no stats kernel, no extra serialization.
//   y <  NC : attention_weights for 256 t's.
//   y == NC : combine chunk ctx partials; out_av = tanh([ctx,h_t] @ W2^T).
// ---------------------------------------------------------------------------
__global__ void k_epi(const float* __restrict__ hs,
                      const float* __restrict__ W2,
                      const float* __restrict__ score,
                      const float* __restrict__ mpart,
                      const float* __restrict__ lpart,
                      const float* __restrict__ ctxp,
                      float* __restrict__ out_av,
                      float* __restrict__ out_aw) {
    int b = blockIdx.x, y = blockIdx.y, tid = threadIdx.x;  // 256 threads

    float M = -1e30f;
    #pragma unroll
    for (int c = 0; c < NC; ++c) M = fmaxf(M, mpart[b * NC + c]);
    float L = 0.f;
    #pragma unroll
    for (int c = 0; c < NC; ++c) L += lpart[b * NC + c] * __expf(mpart[b * NC + c] - M);

    if (y < NC) {
        int t = y * CT + tid;
        out_aw[b * T + t] = __expf(score[b * T + t] - M) * (1.0f / L);
        return;
    }

    // y == NC: attention_vector for batch b
    __shared__ float pre[2 * H];
    float cc = 0.f;
    #pragma unroll
    for (int c = 0; c < NC; ++c)
        cc += ctxp[((size_t)(b * NC + c)) * H + tid] * __expf(mpart[b * NC + c] - M);
    pre[tid]     = cc / L;
    pre[H + tid] = hs[((size_t)(b * T + (T - 1))) * H + tid];
    __syncthreads();
    const float4* w2r = (const float4*)(W2 + (size_t)tid * (2 * H));
    float acc = 0.f;
    #pragma unroll 4
    for (int j = 0; j < (2 * H) / 4; ++j) {
        float4 u = w2r[j];
        acc += pre[4 * j + 0] * u.x + pre[4 * j + 1] * u.y
             + pre[4 * j + 2] * u.z + pre[4 * j + 3] * u.w;
    }
    out_av[b * H + tid] = tanhf(acc);
}

extern "C" void kernel_launch(void* const* d_in, const int* in_sizes, int n_in,
                              void* d_out, int out_size, void* d_ws, size_t ws_size,
                              hipStream_t stream) {
    const float* hs = (const float*)d_in[0];
    const float* W1 = (const float*)d_in[1];
    const float* W2 = (const float*)d_in[2];
    float* out    = (float*)d_out;
    float* out_av = out;              // attention_vector  [B*H  = 8192]
    float* out_aw = out + B * H;      // attention_weights [B*T  = 262144]

    float* ws    = (float*)d_ws;
    float* vpart = ws;                              // VQ*B*H   = 65536
    float* score = vpart + VQ * B * H;              // B*T      = 262144
    float* mpart = score + B * T;                   // B*NC     = 1024
    float* lpart = mpart + B * NC;                  // 1024
    float* ctxp  = lpart + B * NC;                  // B*NC*H   = 262144
    // total ws: ~2.4 MB

    k_v     <<<dim3(B, VQ),     256, 0, stream>>>(hs, W1, vpart);
    k_fused <<<dim3(B, NC),     256, 0, stream>>>(hs, vpart, score, mpart, lpart, ctxp);
    k_epi   <<<dim3(B, NC + 1), 256, 0, stream>>>(hs, W2, score, mpart, lpart, ctxp,
                                                  out_av, out_aw);
}